// Round 10
// baseline (196.235 us; speedup 1.0000x reference)
//
#include <hip/hip_runtime.h>

#define BB 4
#define LL 4096
#define DD 256
#define MAXOFF 160   // max per-batch partial slots (exact bound: 159)

typedef short bf16x8 __attribute__((ext_vector_type(8)));
typedef short bf16x4 __attribute__((ext_vector_type(4)));
typedef float f32x4 __attribute__((ext_vector_type(4)));
typedef unsigned short u16;

__device__ inline u16 f2b(float f) {
    union { float f; unsigned u; } v; v.f = f;
    unsigned r = (v.u + 0x7fffu + ((v.u >> 16) & 1u)) >> 16;  // RNE
    return (u16)r;
}
__device__ inline float b2f(short s) {
    union { unsigned u; float f; } v; v.u = ((unsigned)(unsigned short)s) << 16;
    return v.f;
}

__device__ inline f32x4 mfma32(bf16x8 a, bf16x8 b, f32x4 c) {
    return __builtin_amdgcn_mfma_f32_16x16x32_bf16(a, b, c, 0, 0, 0);
}
__device__ inline f32x4 mfma16(bf16x4 a, bf16x4 b, f32x4 c) {
    return __builtin_amdgcn_mfma_f32_16x16x16bf16_1k(a, b, c, 0, 0, 0);
}

__device__ inline void gl_lds(const u16* g, u16* l) {
    __builtin_amdgcn_global_load_lds(
        (const __attribute__((address_space(1))) void*)g,
        (__attribute__((address_space(3))) void*)l, 16, 0, 0);
}

// ===========================================================================
// Attention partition (round 10): Q-groups of 128 queries (8 tile16s), g in
// [0,32) per batch; k-tiles kt in [0, 4g+4). U(g) = 2g(g+1); 2112 units per
// batch, 128 segments x 16.5 units. Each wave owns TWO 16-query tiles
// (tloc = 2w, 2w+1) -> every LDS K/V chunk feeds 2x the MFMA work (LDS-BW
// bound fix). Partials: bf16, prefix-offset slots:
//   off(g) = sum_{g'<g} nsl(g'), nsl = jlast-j0+1,
//   j0(g) = (4g(g+1)+1)/33, jlast(g) = (4(g+1)(g+2)-1)/33.
//   part[(((b*MAXOFF + off+slot)*8 + tloc)*16 + dt)*256 + lane*4]
// ===========================================================================

__global__ __launch_bounds__(256) void wconv_kernel(
    const float* __restrict__ Wq, const float* __restrict__ Wk,
    const float* __restrict__ Wv, const float* __restrict__ Wo,
    u16* __restrict__ wf, u16* __restrict__ wo16)
{
    const int w = threadIdx.x >> 6, lane = threadIdx.x & 63;
    const int q4 = lane >> 4, ln = lane & 15;
    const int id = blockIdx.x * 4 + w;          // 0..511
    const int mat = id >> 7, rem = id & 127, ct = rem >> 3, ks = rem & 7;
    if (mat < 3) {
        const float* W = (mat == 0) ? Wq : (mat == 1) ? Wk : Wv;
        const float* src = W + (size_t)(ct * 16 + ln) * DD + ks * 32 + q4 * 8;
        float4 f0 = ((const float4*)src)[0], f1 = ((const float4*)src)[1];
        bf16x8 t;
        t[0] = (short)f2b(f0.x); t[1] = (short)f2b(f0.y);
        t[2] = (short)f2b(f0.z); t[3] = (short)f2b(f0.w);
        t[4] = (short)f2b(f1.x); t[5] = (short)f2b(f1.y);
        t[6] = (short)f2b(f1.z); t[7] = (short)f2b(f1.w);
        *(bf16x8*)(wf + (size_t)mat * 65536 + (ct * 8 + ks) * 512 + lane * 8) = t;
    } else {
        const float* src = Wo + (size_t)(ct * 16 + ln) * DD + ks * 32 + q4 * 4;
        float4 f0 = *(const float4*)src;
        float4 f1 = *(const float4*)(src + 16);
        bf16x4 t0, t1;
        t0[0] = (short)f2b(f0.x); t0[1] = (short)f2b(f0.y);
        t0[2] = (short)f2b(f0.z); t0[3] = (short)f2b(f0.w);
        t1[0] = (short)f2b(f1.x); t1[1] = (short)f2b(f1.y);
        t1[2] = (short)f2b(f1.z); t1[3] = (short)f2b(f1.w);
        *(bf16x4*)(wo16 + (size_t)(ct * 16 + 2 * ks) * 256 + lane * 4) = t0;
        *(bf16x4*)(wo16 + (size_t)(ct * 16 + 2 * ks + 1) * 256 + lane * 4) = t1;
    }
}

// ---------------------------------------------------------------------------
// Kernel 1: QKV projection, single pass (unchanged).
// ---------------------------------------------------------------------------
__global__ __launch_bounds__(256, 2) void qkv_kernel(
    const float* __restrict__ x, const u16* __restrict__ wf,
    u16* __restrict__ qf, u16* __restrict__ kf_, u16* __restrict__ vf_)
{
    __shared__ u16 lt[9216];

    const int w = threadIdx.x >> 6, lane = threadIdx.x & 63;
    const int q4 = lane >> 4, ln = lane & 15;
    const int g = blockIdx.x >> 1, half = blockIdx.x & 1;
    const int m0 = g * 64;

    bf16x8 a[8];
    {
        const float* xrow = x + (size_t)(m0 + w * 16 + ln) * DD;
        #pragma unroll
        for (int ks = 0; ks < 8; ++ks) {
            const float4* p = (const float4*)(xrow + ks * 32 + q4 * 8);
            float4 f0 = p[0], f1 = p[1];
            bf16x8 t;
            t[0] = (short)f2b(f0.x); t[1] = (short)f2b(f0.y);
            t[2] = (short)f2b(f0.z); t[3] = (short)f2b(f0.w);
            t[4] = (short)f2b(f1.x); t[5] = (short)f2b(f1.y);
            t[6] = (short)f2b(f1.z); t[7] = (short)f2b(f1.w);
            a[ks] = t;
        }
    }

    f32x4 acc0[8], acc1[8], acc2[8];
    #pragma unroll
    for (int cl = 0; cl < 8; ++cl) {
        acc0[cl] = f32x4{0.f, 0.f, 0.f, 0.f};
        acc1[cl] = f32x4{0.f, 0.f, 0.f, 0.f};
        acc2[cl] = f32x4{0.f, 0.f, 0.f, 0.f};
    }

    #pragma unroll
    for (int ks = 0; ks < 8; ++ks) {
        #pragma unroll
        for (int cl = 0; cl < 8; ++cl) {
            const size_t off = ((size_t)(half * 8 + cl) * 8 + ks) * 512 + lane * 8;
            bf16x8 b0 = *(const bf16x8*)(wf + off);
            bf16x8 b1 = *(const bf16x8*)(wf + 65536 + off);
            bf16x8 b2 = *(const bf16x8*)(wf + 131072 + off);
            acc0[cl] = mfma32(a[ks], b0, acc0[cl]);
            acc1[cl] = mfma32(a[ks], b1, acc1[cl]);
            acc2[cl] = mfma32(a[ks], b2, acc2[cl]);
        }
    }

    #pragma unroll
    for (int cl = 0; cl < 8; ++cl)
        #pragma unroll
        for (int r = 0; r < 4; ++r)
            lt[(w * 16 + q4 * 4 + r) * 136 + cl * 16 + ln] = f2b(acc0[cl][r]);
    __syncthreads();
    {
        const int T_l = w >> 1, h = w & 1;
        const int bigT = g * 2 + T_l;
        #pragma unroll
        for (int ksl = 0; ksl < 4; ++ksl) {
            const int ks = half * 4 + ksl;
            bf16x8 af = *(const bf16x8*)&lt[(T_l * 32 + h * 16 + ln) * 136 + ksl * 32 + q4 * 8];
            *(bf16x8*)(qf + (size_t)((bigT * 2 + h) * 8 + ks) * 512 + lane * 8) = af;
        }
    }
    __syncthreads();

    #pragma unroll
    for (int cl = 0; cl < 8; ++cl)
        #pragma unroll
        for (int r = 0; r < 4; ++r)
            lt[(w * 16 + q4 * 4 + r) * 136 + cl * 16 + ln] = f2b(acc1[cl][r]);
    __syncthreads();
    {
        const int T_l = w >> 1, h = w & 1;
        const int bigT = g * 2 + T_l;
        #pragma unroll
        for (int ksl = 0; ksl < 4; ++ksl) {
            const int ks = half * 4 + ksl;
            bf16x8 af = *(const bf16x8*)&lt[(T_l * 32 + h * 16 + ln) * 136 + ksl * 32 + q4 * 8];
            *(bf16x8*)(kf_ + (size_t)((bigT * 2 + h) * 8 + ks) * 512 + lane * 8) = af;
        }
    }
    __syncthreads();

    #pragma unroll
    for (int cl = 0; cl < 8; ++cl)
        #pragma unroll
        for (int r = 0; r < 4; ++r)
            lt[(cl * 16 + ln) * 72 + w * 16 + q4 * 4 + r] = f2b(acc2[cl][r]);
    __syncthreads();
    {
        const int kt32_l = w & 1;
        const int kt32g = g * 2 + kt32_l;
        const int tok0 = kt32_l * 32 + q4 * 4;
        #pragma unroll
        for (int i = 0; i < 4; ++i) {
            const int dt_l = (w >> 1) * 4 + i;
            const int dtg = half * 8 + dt_l;
            const int dim_l = dt_l * 16 + ln;
            bf16x4 lo = *(const bf16x4*)&lt[dim_l * 72 + tok0];
            bf16x4 hi = *(const bf16x4*)&lt[dim_l * 72 + tok0 + 16];
            bf16x8 t;
            t[0] = lo[0]; t[1] = lo[1]; t[2] = lo[2]; t[3] = lo[3];
            t[4] = hi[0]; t[5] = hi[1]; t[6] = hi[2]; t[7] = hi[3];
            *(bf16x8*)(vf_ + (size_t)(kt32g * 16 + dtg) * 512 + lane * 8) = t;
        }
    }
}

// ---------------------------------------------------------------------------
// Kernel 2: causal ReLU attention — 32 queries/wave (LDS-BW fix) + equal-work
// flattened segments. 512 blocks (2/CU): b = (i>>1)&3, segment j.
// ---------------------------------------------------------------------------
__global__ __launch_bounds__(256, 2) void attn_kernel(
    const u16* __restrict__ qf, const u16* __restrict__ kfr,
    const u16* __restrict__ vfr, u16* __restrict__ part)
{
    __shared__ u16 buf[2][32][512];   // 64 KB

    const int i = blockIdx.x;
    const int b = (i >> 1) & 3;
    const int j = ((i >> 3) << 1) | (i & 1);    // segment 0..127

    const int w = threadIdx.x >> 6, lane = threadIdx.x & 63;
    const int q4 = lane >> 4, ln = lane & 15;

    const int u0 = (33 * j) >> 1;
    const int u1 = (33 * (j + 1)) >> 1;

    // decode g: largest g with 2g(g+1) <= u0
    int g = (int)((sqrtf((float)(2 * u0 + 1)) - 1.0f) * 0.5f);
    while (2 * (g + 1) * (g + 2) <= u0) ++g;
    while (2 * g * (g + 1) > u0) --g;
    int kt = u0 - 2 * g * (g + 1);
    int u = u0;

    // prefix offset off(g) for the initial group
    int off = 0;
    for (int g2 = 0; g2 < g; ++g2) {
        const int j0 = (4 * g2 * (g2 + 1) + 1) / 33;
        const int jl = (4 * (g2 + 1) * (g2 + 2) - 1) / 33;
        off += jl - j0 + 1;
    }

    // prologue: stage k-tile kt into buf[u0&1]
    {
        const size_t cb = (size_t)((b * 128 + kt) * 16) * 512;
        #pragma unroll
        for (int c4 = 0; c4 < 8; ++c4) {
            const int c = w * 8 + c4;
            const u16* gsrc = ((c < 16) ? (kfr + cb + c * 512)
                                        : (vfr + cb + (c - 16) * 512)) + lane * 8;
            gl_lds(gsrc, &buf[u0 & 1][c][0]);
        }
    }

    while (u < u1) {
        const int ktend = 4 * g + 4;
        const int rem = u1 - u;
        const int kt_stop = (ktend < kt + rem) ? ktend : (kt + rem);
        const int t0 = g * 8 + 2 * w;            // tile16 for qi=0
        const int qg0 = t0 * 16 + ln;            // query col, qi=0
        const int qg1 = qg0 + 16;                // query col, qi=1
        const float inv0 = 1.0f / (float)(qg0 > 1 ? qg0 : 1);
        const float inv1 = 1.0f / (float)qg1;    // qg1 >= 16

        // Q B-frags for both tiles of this wave
        bf16x8 qB0[8], qB1[8];
        {
            const u16* qb0 = qf + (size_t)(t0 * 8) * 512 + (size_t)b * (128 * 16 * 512) + lane * 8;
            #pragma unroll
            for (int ks = 0; ks < 8; ++ks) {
                qB0[ks] = *(const bf16x8*)(qb0 + ks * 512);
                qB1[ks] = *(const bf16x8*)(qb0 + (8 + ks) * 512);
            }
        }

        f32x4 oacc0[16], oacc1[16];
        #pragma unroll
        for (int dt = 0; dt < 16; ++dt) {
            oacc0[dt] = f32x4{0.f, 0.f, 0.f, 0.f};
            oacc1[dt] = f32x4{0.f, 0.f, 0.f, 0.f};
        }

        #pragma unroll 1
        for (; kt < kt_stop; ++kt, ++u) {
            const int cur = u & 1;
            __syncthreads();

            if (u + 1 < u1) {
                const int ktn = (kt + 1 < ktend) ? (kt + 1) : 0;
                const size_t cb = (size_t)((b * 128 + ktn) * 16) * 512;
                #pragma unroll
                for (int c4 = 0; c4 < 8; ++c4) {
                    const int c = w * 8 + c4;
                    const u16* gsrc = ((c < 16) ? (kfr + cb + c * 512)
                                                : (vfr + cb + (c - 16) * 512)) + lane * 8;
                    gl_lds(gsrc, &buf[cur ^ 1][c][0]);
                }
            }

            // ---- S^T = K Q^T : 4 C-tiles (2 kh x 2 qi), 32 mfma32 ----
            f32x4 s00 = f32x4{0.f, 0.f, 0.f, 0.f};
            f32x4 s10 = f32x4{0.f, 0.f, 0.f, 0.f};
            f32x4 s01 = f32x4{0.f, 0.f, 0.f, 0.f};
            f32x4 s11 = f32x4{0.f, 0.f, 0.f, 0.f};
            #pragma unroll
            for (int ks = 0; ks < 8; ++ks) {
                bf16x8 kf0 = *(const bf16x8*)&buf[cur][ks][lane * 8];
                bf16x8 kf1 = *(const bf16x8*)&buf[cur][8 + ks][lane * 8];
                s00 = mfma32(kf0, qB0[ks], s00);
                s10 = mfma32(kf1, qB0[ks], s10);
                s01 = mfma32(kf0, qB1[ks], s01);
                s11 = mfma32(kf1, qB1[ks], s11);
            }

            // ---- mask/relu/scale, pack P^T (C-layout == K=16 B-frag) ----
            const int d0 = kt * 32 + q4 * 4 - qg0;   // key - query(qi=0), kh=0
            bf16x4 p00, p10, p01, p11;
            #pragma unroll
            for (int rr = 0; rr < 4; ++rr) {
                float v00 = (d0 + rr > 0)      ? 0.f : fmaxf(s00[rr], 0.f) * inv0;
                float v10 = (d0 + 16 + rr > 0) ? 0.f : fmaxf(s10[rr], 0.f) * inv0;
                float v01 = (d0 - 16 + rr > 0) ? 0.f : fmaxf(s01[rr], 0.f) * inv1;
                float v11 = (d0 + rr > 0)      ? 0.f : fmaxf(s11[rr], 0.f) * inv1;
                p00[rr] = (short)f2b(v00);
                p10[rr] = (short)f2b(v10);
                p01[rr] = (short)f2b(v01);
                p11[rr] = (short)f2b(v11);
            }

            // ---- O^T += V^T P^T : each V chunk feeds BOTH q-tiles ----
            #pragma unroll
            for (int dt = 0; dt < 16; ++dt) {
                bf16x8 vv = *(const bf16x8*)&buf[cur][16 + dt][lane * 8];
                bf16x4 a0 = __builtin_shufflevector(vv, vv, 0, 1, 2, 3);
                bf16x4 a1 = __builtin_shufflevector(vv, vv, 4, 5, 6, 7);
                oacc0[dt] = mfma16(a0, p00, oacc0[dt]);
                oacc0[dt] = mfma16(a1, p10, oacc0[dt]);
                oacc1[dt] = mfma16(a0, p01, oacc1[dt]);
                oacc1[dt] = mfma16(a1, p11, oacc1[dt]);
            }
        }

        // ---- flush both tiles' partials (bf16) ----
        {
            const int j0g = (4 * g * (g + 1) + 1) / 33;
            const int gslot = off + (j - j0g);
            u16* pb0 = part + ((((size_t)b * MAXOFF + gslot) * 8 + 2 * w) * 16) * 256 + lane * 4;
            u16* pb1 = pb0 + 16 * 256;
            #pragma unroll
            for (int dt = 0; dt < 16; ++dt) {
                bf16x4 t0v, t1v;
                t0v[0] = (short)f2b(oacc0[dt][0]); t0v[1] = (short)f2b(oacc0[dt][1]);
                t0v[2] = (short)f2b(oacc0[dt][2]); t0v[3] = (short)f2b(oacc0[dt][3]);
                t1v[0] = (short)f2b(oacc1[dt][0]); t1v[1] = (short)f2b(oacc1[dt][1]);
                t1v[2] = (short)f2b(oacc1[dt][2]); t1v[3] = (short)f2b(oacc1[dt][3]);
                *(bf16x4*)(pb0 + dt * 256) = t0v;
                *(bf16x4*)(pb1 + dt * 256) = t1v;
            }
            // advance prefix offset to g+1
            off += ((4 * (g + 1) * (g + 2) - 1) / 33) - j0g + 1;
        }
        ++g;
        kt = 0;
    }
}

// ---------------------------------------------------------------------------
// Kernel 3: fused reduce + output projection. 512 blocks x 4 waves; block =
// 32 tokens (2 tile16s). Phase A sums nsl(g) bf16 partial slots -> LDS;
// Phase B: out^T = Wo ctx^T via mfma16, direct fp32 stores.
// ---------------------------------------------------------------------------
__global__ __launch_bounds__(256, 2) void oproj_kernel(
    const u16* __restrict__ part, const u16* __restrict__ wo16,
    float* __restrict__ out)
{
    __shared__ u16 cb[2 * 16 * 256];   // 16 KB

    const int w = threadIdx.x >> 6, lane = threadIdx.x & 63;
    const int q4 = lane >> 4, ln = lane & 15;
    const int g32 = blockIdx.x;        // 32-token group, 0..511
    const int b = g32 >> 7, gb = g32 & 127;
    const int g = gb >> 2;             // 128-query group
    const int tloc_base = (gb & 3) * 2;

    int off = 0;
    for (int g2 = 0; g2 < g; ++g2) {
        const int j0 = (4 * g2 * (g2 + 1) + 1) / 33;
        const int jl = (4 * (g2 + 1) * (g2 + 2) - 1) / 33;
        off += jl - j0 + 1;
    }
    const int j0g = (4 * g * (g + 1) + 1) / 33;
    const int jlg = (4 * (g + 1) * (g + 2) - 1) / 33;
    const int nsl = jlg - j0g + 1;

    // Phase A: 32 chunks; wave w handles 8
    #pragma unroll
    for (int c4 = 0; c4 < 8; ++c4) {
        const int idx = w * 8 + c4;
        const int tokt = idx >> 4, dt = idx & 15;
        const int tloc = tloc_base + tokt;
        f32x4 s = f32x4{0.f, 0.f, 0.f, 0.f};
        for (int sl = 0; sl < nsl; ++sl) {
            const u16* p = part + ((((size_t)b * MAXOFF + off + sl) * 8 + tloc) * 16 + dt) * 256 + lane * 4;
            bf16x4 pv = *(const bf16x4*)p;
            s[0] += b2f(pv[0]); s[1] += b2f(pv[1]);
            s[2] += b2f(pv[2]); s[3] += b2f(pv[3]);
        }
        bf16x4 t;
        t[0] = (short)f2b(s[0]); t[1] = (short)f2b(s[1]);
        t[2] = (short)f2b(s[2]); t[3] = (short)f2b(s[3]);
        *(bf16x4*)&cb[(tokt * 16 + dt) * 256 + lane * 4] = t;
    }
    __syncthreads();

    // Phase B: wave w -> d-tiles [w*4, w*4+4)
    #pragma unroll
    for (int c4 = 0; c4 < 4; ++c4) {
        const int ct = w * 4 + c4;
        f32x4 acc0 = f32x4{0.f, 0.f, 0.f, 0.f};
        f32x4 acc1 = f32x4{0.f, 0.f, 0.f, 0.f};
        #pragma unroll
        for (int dt = 0; dt < 16; ++dt) {
            bf16x4 A = *(const bf16x4*)(wo16 + (size_t)(ct * 16 + dt) * 256 + lane * 4);
            bf16x4 B0 = *(const bf16x4*)&cb[(0 * 16 + dt) * 256 + lane * 4];
            bf16x4 B1 = *(const bf16x4*)&cb[(1 * 16 + dt) * 256 + lane * 4];
            acc0 = mfma16(A, B0, acc0);
            acc1 = mfma16(A, B1, acc1);
        }
        float* o0 = out + (size_t)(g32 * 32 + 0 * 16 + ln) * DD + ct * 16 + q4 * 4;
        float* o1 = out + (size_t)(g32 * 32 + 1 * 16 + ln) * DD + ct * 16 + q4 * 4;
        *(f32x4*)o0 = acc0;
        *(f32x4*)o1 = acc1;
    }
}

extern "C" void kernel_launch(void* const* d_in, const int* in_sizes, int n_in,
                              void* d_out, int out_size, void* d_ws, size_t ws_size,
                              hipStream_t stream)
{
    const float* x  = (const float*)d_in[0];
    const float* Wq = (const float*)d_in[1];
    const float* Wk = (const float*)d_in[2];
    const float* Wv = (const float*)d_in[3];
    const float* Wo = (const float*)d_in[4];
    float* out = (float*)d_out;

    const size_t nW = (size_t)DD * DD;        // 65536
    const size_t nX = (size_t)BB * LL * DD;   // 4,194,304

    u16* wf   = (u16*)d_ws;                   // Wq,Wk,Wv B-frag order (384 KB)
    u16* wo16 = wf + 3 * nW;                  // Wo K=16 A-frag order (128 KB)
    u16* qfr  = wf + 4 * nW;                  // 8 MB
    u16* kfr  = qfr + nX;                     // 8 MB
    u16* vfr  = kfr + nX;                     // 8 MB
    u16* part = vfr + nX;                     // 4*160*8*16*256 bf16 = 41.9 MB

    wconv_kernel<<<dim3(128), dim3(256), 0, stream>>>(Wq, Wk, Wv, Wo, wf, wo16);
    qkv_kernel<<<dim3(512), dim3(256), 0, stream>>>(x, wf, qfr, kfr, vfr);
    attn_kernel<<<dim3(512), dim3(256), 0, stream>>>(qfr, kfr, vfr, part);
    oproj_kernel<<<dim3(512), dim3(256), 0, stream>>>(part, wo16, out);
}

// Round 11
// 188.998 us; speedup vs baseline: 1.0383x; 1.0383x over previous
//
#include <hip/hip_runtime.h>

#define BB 4
#define LL 4096
#define DD 256
#define MAXOFF 160   // max per-batch partial slots (exact bound: 159)

typedef short bf16x8 __attribute__((ext_vector_type(8)));
typedef short bf16x4 __attribute__((ext_vector_type(4)));
typedef float f32x4 __attribute__((ext_vector_type(4)));
typedef unsigned u32x4 __attribute__((ext_vector_type(4)));
typedef unsigned short u16;

__device__ inline u16 f2b(float f) {
    union { float f; unsigned u; } v; v.f = f;
    unsigned r = (v.u + 0x7fffu + ((v.u >> 16) & 1u)) >> 16;  // RNE
    return (u16)r;
}
__device__ inline float b2f(short s) {
    union { unsigned u; float f; } v; v.u = ((unsigned)(unsigned short)s) << 16;
    return v.f;
}
// pack 2 fp32 -> 2 bf16 (TRUNCATE) in one v_perm_b32:
// dst = [lo>>16 (bytes a.b2,a.b3), hi>>16 (bytes b.b2,b.b3)]
__device__ inline unsigned pk2(float lo, float hi) {
    union { float f; unsigned u; } a, b; a.f = lo; b.f = hi;
    return __builtin_amdgcn_perm(b.u, a.u, 0x07060302u);
}

__device__ inline f32x4 mfma32(bf16x8 a, bf16x8 b, f32x4 c) {
    return __builtin_amdgcn_mfma_f32_16x16x32_bf16(a, b, c, 0, 0, 0);
}
__device__ inline f32x4 mfma16(bf16x4 a, bf16x4 b, f32x4 c) {
    return __builtin_amdgcn_mfma_f32_16x16x16bf16_1k(a, b, c, 0, 0, 0);
}

__device__ inline void gl_lds(const u16* g, u16* l) {
    __builtin_amdgcn_global_load_lds(
        (const __attribute__((address_space(1))) void*)g,
        (__attribute__((address_space(3))) void*)l, 16, 0, 0);
}

// ===========================================================================
// Attention partition (unchanged from round 10): 128-query groups, g in
// [0,32)/batch; kt in [0,4g+4); U(g)=2g(g+1); 128 segments x 16.5 units.
// Wave owns TWO 16-query tiles. NEW (round 11): PV uses K=32 mfma32 — the
// packed V chunk (keys q4*4+j | 16+q4*4+j) and concatenated P^T C-regs
// (s_kh0 || s_kh1) share the same k-permutation, so one mfma32 replaces two
// mfma16 + shufflevector extracts. P packed via v_perm truncation (1 VALU
// per 2 elems) instead of software-RNE.
// ===========================================================================

__global__ __launch_bounds__(256) void wconv_kernel(
    const float* __restrict__ Wq, const float* __restrict__ Wk,
    const float* __restrict__ Wv, const float* __restrict__ Wo,
    u16* __restrict__ wf, u16* __restrict__ wo16)
{
    const int w = threadIdx.x >> 6, lane = threadIdx.x & 63;
    const int q4 = lane >> 4, ln = lane & 15;
    const int id = blockIdx.x * 4 + w;          // 0..511
    const int mat = id >> 7, rem = id & 127, ct = rem >> 3, ks = rem & 7;
    if (mat < 3) {
        const float* W = (mat == 0) ? Wq : (mat == 1) ? Wk : Wv;
        const float* src = W + (size_t)(ct * 16 + ln) * DD + ks * 32 + q4 * 8;
        float4 f0 = ((const float4*)src)[0], f1 = ((const float4*)src)[1];
        bf16x8 t;
        t[0] = (short)f2b(f0.x); t[1] = (short)f2b(f0.y);
        t[2] = (short)f2b(f0.z); t[3] = (short)f2b(f0.w);
        t[4] = (short)f2b(f1.x); t[5] = (short)f2b(f1.y);
        t[6] = (short)f2b(f1.z); t[7] = (short)f2b(f1.w);
        *(bf16x8*)(wf + (size_t)mat * 65536 + (ct * 8 + ks) * 512 + lane * 8) = t;
    } else {
        const float* src = Wo + (size_t)(ct * 16 + ln) * DD + ks * 32 + q4 * 4;
        float4 f0 = *(const float4*)src;
        float4 f1 = *(const float4*)(src + 16);
        bf16x4 t0, t1;
        t0[0] = (short)f2b(f0.x); t0[1] = (short)f2b(f0.y);
        t0[2] = (short)f2b(f0.z); t0[3] = (short)f2b(f0.w);
        t1[0] = (short)f2b(f1.x); t1[1] = (short)f2b(f1.y);
        t1[2] = (short)f2b(f1.z); t1[3] = (short)f2b(f1.w);
        *(bf16x4*)(wo16 + (size_t)(ct * 16 + 2 * ks) * 256 + lane * 4) = t0;
        *(bf16x4*)(wo16 + (size_t)(ct * 16 + 2 * ks + 1) * 256 + lane * 4) = t1;
    }
}

// ---------------------------------------------------------------------------
// Kernel 1: QKV projection, single pass (unchanged).
// ---------------------------------------------------------------------------
__global__ __launch_bounds__(256, 2) void qkv_kernel(
    const float* __restrict__ x, const u16* __restrict__ wf,
    u16* __restrict__ qf, u16* __restrict__ kf_, u16* __restrict__ vf_)
{
    __shared__ u16 lt[9216];

    const int w = threadIdx.x >> 6, lane = threadIdx.x & 63;
    const int q4 = lane >> 4, ln = lane & 15;
    const int g = blockIdx.x >> 1, half = blockIdx.x & 1;
    const int m0 = g * 64;

    bf16x8 a[8];
    {
        const float* xrow = x + (size_t)(m0 + w * 16 + ln) * DD;
        #pragma unroll
        for (int ks = 0; ks < 8; ++ks) {
            const float4* p = (const float4*)(xrow + ks * 32 + q4 * 8);
            float4 f0 = p[0], f1 = p[1];
            bf16x8 t;
            t[0] = (short)f2b(f0.x); t[1] = (short)f2b(f0.y);
            t[2] = (short)f2b(f0.z); t[3] = (short)f2b(f0.w);
            t[4] = (short)f2b(f1.x); t[5] = (short)f2b(f1.y);
            t[6] = (short)f2b(f1.z); t[7] = (short)f2b(f1.w);
            a[ks] = t;
        }
    }

    f32x4 acc0[8], acc1[8], acc2[8];
    #pragma unroll
    for (int cl = 0; cl < 8; ++cl) {
        acc0[cl] = f32x4{0.f, 0.f, 0.f, 0.f};
        acc1[cl] = f32x4{0.f, 0.f, 0.f, 0.f};
        acc2[cl] = f32x4{0.f, 0.f, 0.f, 0.f};
    }

    #pragma unroll
    for (int ks = 0; ks < 8; ++ks) {
        #pragma unroll
        for (int cl = 0; cl < 8; ++cl) {
            const size_t off = ((size_t)(half * 8 + cl) * 8 + ks) * 512 + lane * 8;
            bf16x8 b0 = *(const bf16x8*)(wf + off);
            bf16x8 b1 = *(const bf16x8*)(wf + 65536 + off);
            bf16x8 b2 = *(const bf16x8*)(wf + 131072 + off);
            acc0[cl] = mfma32(a[ks], b0, acc0[cl]);
            acc1[cl] = mfma32(a[ks], b1, acc1[cl]);
            acc2[cl] = mfma32(a[ks], b2, acc2[cl]);
        }
    }

    #pragma unroll
    for (int cl = 0; cl < 8; ++cl)
        #pragma unroll
        for (int r = 0; r < 4; ++r)
            lt[(w * 16 + q4 * 4 + r) * 136 + cl * 16 + ln] = f2b(acc0[cl][r]);
    __syncthreads();
    {
        const int T_l = w >> 1, h = w & 1;
        const int bigT = g * 2 + T_l;
        #pragma unroll
        for (int ksl = 0; ksl < 4; ++ksl) {
            const int ks = half * 4 + ksl;
            bf16x8 af = *(const bf16x8*)&lt[(T_l * 32 + h * 16 + ln) * 136 + ksl * 32 + q4 * 8];
            *(bf16x8*)(qf + (size_t)((bigT * 2 + h) * 8 + ks) * 512 + lane * 8) = af;
        }
    }
    __syncthreads();

    #pragma unroll
    for (int cl = 0; cl < 8; ++cl)
        #pragma unroll
        for (int r = 0; r < 4; ++r)
            lt[(w * 16 + q4 * 4 + r) * 136 + cl * 16 + ln] = f2b(acc1[cl][r]);
    __syncthreads();
    {
        const int T_l = w >> 1, h = w & 1;
        const int bigT = g * 2 + T_l;
        #pragma unroll
        for (int ksl = 0; ksl < 4; ++ksl) {
            const int ks = half * 4 + ksl;
            bf16x8 af = *(const bf16x8*)&lt[(T_l * 32 + h * 16 + ln) * 136 + ksl * 32 + q4 * 8];
            *(bf16x8*)(kf_ + (size_t)((bigT * 2 + h) * 8 + ks) * 512 + lane * 8) = af;
        }
    }
    __syncthreads();

    #pragma unroll
    for (int cl = 0; cl < 8; ++cl)
        #pragma unroll
        for (int r = 0; r < 4; ++r)
            lt[(cl * 16 + ln) * 72 + w * 16 + q4 * 4 + r] = f2b(acc2[cl][r]);
    __syncthreads();
    {
        const int kt32_l = w & 1;
        const int kt32g = g * 2 + kt32_l;
        const int tok0 = kt32_l * 32 + q4 * 4;
        #pragma unroll
        for (int i = 0; i < 4; ++i) {
            const int dt_l = (w >> 1) * 4 + i;
            const int dtg = half * 8 + dt_l;
            const int dim_l = dt_l * 16 + ln;
            bf16x4 lo = *(const bf16x4*)&lt[dim_l * 72 + tok0];
            bf16x4 hi = *(const bf16x4*)&lt[dim_l * 72 + tok0 + 16];
            bf16x8 t;
            t[0] = lo[0]; t[1] = lo[1]; t[2] = lo[2]; t[3] = lo[3];
            t[4] = hi[0]; t[5] = hi[1]; t[6] = hi[2]; t[7] = hi[3];
            *(bf16x8*)(vf_ + (size_t)(kt32g * 16 + dtg) * 512 + lane * 8) = t;
        }
    }
}

// ---------------------------------------------------------------------------
// Kernel 2: causal ReLU attention — 32 queries/wave, equal-work segments,
// K=32 PV MFMA, perm-packed P.
// ---------------------------------------------------------------------------
__global__ __launch_bounds__(256, 2) void attn_kernel(
    const u16* __restrict__ qf, const u16* __restrict__ kfr,
    const u16* __restrict__ vfr, u16* __restrict__ part)
{
    __shared__ u16 buf[2][32][512];   // 64 KB

    const int i = blockIdx.x;
    const int b = (i >> 1) & 3;
    const int j = ((i >> 3) << 1) | (i & 1);    // segment 0..127

    const int w = threadIdx.x >> 6, lane = threadIdx.x & 63;
    const int q4 = lane >> 4, ln = lane & 15;

    const int u0 = (33 * j) >> 1;
    const int u1 = (33 * (j + 1)) >> 1;

    // decode g: largest g with 2g(g+1) <= u0
    int g = (int)((sqrtf((float)(2 * u0 + 1)) - 1.0f) * 0.5f);
    while (2 * (g + 1) * (g + 2) <= u0) ++g;
    while (2 * g * (g + 1) > u0) --g;
    int kt = u0 - 2 * g * (g + 1);
    int u = u0;

    // prefix offset off(g) for the initial group
    int off = 0;
    for (int g2 = 0; g2 < g; ++g2) {
        const int j0 = (4 * g2 * (g2 + 1) + 1) / 33;
        const int jl = (4 * (g2 + 1) * (g2 + 2) - 1) / 33;
        off += jl - j0 + 1;
    }

    // prologue: stage k-tile kt into buf[u0&1]
    {
        const size_t cb = (size_t)((b * 128 + kt) * 16) * 512;
        #pragma unroll
        for (int c4 = 0; c4 < 8; ++c4) {
            const int c = w * 8 + c4;
            const u16* gsrc = ((c < 16) ? (kfr + cb + c * 512)
                                        : (vfr + cb + (c - 16) * 512)) + lane * 8;
            gl_lds(gsrc, &buf[u0 & 1][c][0]);
        }
    }

    while (u < u1) {
        const int ktend = 4 * g + 4;
        const int rem = u1 - u;
        const int kt_stop = (ktend < kt + rem) ? ktend : (kt + rem);
        const int t0 = g * 8 + 2 * w;            // tile16 for qi=0
        const int qg0 = t0 * 16 + ln;            // query col, qi=0
        const int qg1 = qg0 + 16;                // query col, qi=1
        const float inv0 = 1.0f / (float)(qg0 > 1 ? qg0 : 1);
        const float inv1 = 1.0f / (float)qg1;    // qg1 >= 16

        // Q B-frags for both tiles of this wave
        bf16x8 qB0[8], qB1[8];
        {
            const u16* qb0 = qf + (size_t)(t0 * 8) * 512 + (size_t)b * (128 * 16 * 512) + lane * 8;
            #pragma unroll
            for (int ks = 0; ks < 8; ++ks) {
                qB0[ks] = *(const bf16x8*)(qb0 + ks * 512);
                qB1[ks] = *(const bf16x8*)(qb0 + (8 + ks) * 512);
            }
        }

        f32x4 oacc0[16], oacc1[16];
        #pragma unroll
        for (int dt = 0; dt < 16; ++dt) {
            oacc0[dt] = f32x4{0.f, 0.f, 0.f, 0.f};
            oacc1[dt] = f32x4{0.f, 0.f, 0.f, 0.f};
        }

        #pragma unroll 1
        for (; kt < kt_stop; ++kt, ++u) {
            const int cur = u & 1;
            __syncthreads();

            if (u + 1 < u1) {
                const int ktn = (kt + 1 < ktend) ? (kt + 1) : 0;
                const size_t cb = (size_t)((b * 128 + ktn) * 16) * 512;
                #pragma unroll
                for (int c4 = 0; c4 < 8; ++c4) {
                    const int c = w * 8 + c4;
                    const u16* gsrc = ((c < 16) ? (kfr + cb + c * 512)
                                                : (vfr + cb + (c - 16) * 512)) + lane * 8;
                    gl_lds(gsrc, &buf[cur ^ 1][c][0]);
                }
            }

            // ---- S^T = K Q^T : 4 C-tiles (2 kh x 2 qi), 32 mfma32 ----
            f32x4 s00 = f32x4{0.f, 0.f, 0.f, 0.f};
            f32x4 s10 = f32x4{0.f, 0.f, 0.f, 0.f};
            f32x4 s01 = f32x4{0.f, 0.f, 0.f, 0.f};
            f32x4 s11 = f32x4{0.f, 0.f, 0.f, 0.f};
            #pragma unroll
            for (int ks = 0; ks < 8; ++ks) {
                bf16x8 kf0 = *(const bf16x8*)&buf[cur][ks][lane * 8];
                bf16x8 kf1 = *(const bf16x8*)&buf[cur][8 + ks][lane * 8];
                s00 = mfma32(kf0, qB0[ks], s00);
                s10 = mfma32(kf1, qB0[ks], s10);
                s01 = mfma32(kf0, qB1[ks], s01);
                s11 = mfma32(kf1, qB1[ks], s11);
            }

            // ---- mask/relu/scale -> P^T packed as K=32 B-frags.
            // Position (q4,j): j<4 -> key kt*32+q4*4+j (from s_kh0 reg j),
            //                  j>=4 -> key kt*32+16+q4*4+(j-4) (from s_kh1).
            // Same k-permutation as the packed V chunk -> mfma32-compatible.
            const int d0 = kt * 32 + q4 * 4 - qg0;   // key - query(qi=0), kh=0
            float v00[4], v10[4], v01[4], v11[4];
            #pragma unroll
            for (int rr = 0; rr < 4; ++rr) {
                v00[rr] = (d0 + rr > 0)      ? 0.f : fmaxf(s00[rr], 0.f) * inv0;
                v10[rr] = (d0 + 16 + rr > 0) ? 0.f : fmaxf(s10[rr], 0.f) * inv0;
                v01[rr] = (d0 - 16 + rr > 0) ? 0.f : fmaxf(s01[rr], 0.f) * inv1;
                v11[rr] = (d0 + rr > 0)      ? 0.f : fmaxf(s11[rr], 0.f) * inv1;
            }
            union { u32x4 u; bf16x8 h; } c0, c1;
            c0.u[0] = pk2(v00[0], v00[1]); c0.u[1] = pk2(v00[2], v00[3]);
            c0.u[2] = pk2(v10[0], v10[1]); c0.u[3] = pk2(v10[2], v10[3]);
            c1.u[0] = pk2(v01[0], v01[1]); c1.u[1] = pk2(v01[2], v01[3]);
            c1.u[2] = pk2(v11[0], v11[1]); c1.u[3] = pk2(v11[2], v11[3]);

            // ---- O^T += V^T P^T : one K=32 mfma per (dt, qi) ----
            #pragma unroll
            for (int dt = 0; dt < 16; ++dt) {
                bf16x8 vv = *(const bf16x8*)&buf[cur][16 + dt][lane * 8];
                oacc0[dt] = mfma32(vv, c0.h, oacc0[dt]);
                oacc1[dt] = mfma32(vv, c1.h, oacc1[dt]);
            }
        }

        // ---- flush both tiles' partials (bf16, RNE) ----
        {
            const int j0g = (4 * g * (g + 1) + 1) / 33;
            const int gslot = off + (j - j0g);
            u16* pb0 = part + ((((size_t)b * MAXOFF + gslot) * 8 + 2 * w) * 16) * 256 + lane * 4;
            u16* pb1 = pb0 + 16 * 256;
            #pragma unroll
            for (int dt = 0; dt < 16; ++dt) {
                bf16x4 t0v, t1v;
                t0v[0] = (short)f2b(oacc0[dt][0]); t0v[1] = (short)f2b(oacc0[dt][1]);
                t0v[2] = (short)f2b(oacc0[dt][2]); t0v[3] = (short)f2b(oacc0[dt][3]);
                t1v[0] = (short)f2b(oacc1[dt][0]); t1v[1] = (short)f2b(oacc1[dt][1]);
                t1v[2] = (short)f2b(oacc1[dt][2]); t1v[3] = (short)f2b(oacc1[dt][3]);
                *(bf16x4*)(pb0 + dt * 256) = t0v;
                *(bf16x4*)(pb1 + dt * 256) = t1v;
            }
            off += ((4 * (g + 1) * (g + 2) - 1) / 33) - j0g + 1;
        }
        ++g;
        kt = 0;
    }
}

// ---------------------------------------------------------------------------
// Kernel 3: fused reduce + output projection (unchanged).
// ---------------------------------------------------------------------------
__global__ __launch_bounds__(256, 2) void oproj_kernel(
    const u16* __restrict__ part, const u16* __restrict__ wo16,
    float* __restrict__ out)
{
    __shared__ u16 cb[2 * 16 * 256];   // 16 KB

    const int w = threadIdx.x >> 6, lane = threadIdx.x & 63;
    const int q4 = lane >> 4, ln = lane & 15;
    const int g32 = blockIdx.x;        // 32-token group, 0..511
    const int b = g32 >> 7, gb = g32 & 127;
    const int g = gb >> 2;             // 128-query group
    const int tloc_base = (gb & 3) * 2;

    int off = 0;
    for (int g2 = 0; g2 < g; ++g2) {
        const int j0 = (4 * g2 * (g2 + 1) + 1) / 33;
        const int jl = (4 * (g2 + 1) * (g2 + 2) - 1) / 33;
        off += jl - j0 + 1;
    }
    const int j0g = (4 * g * (g + 1) + 1) / 33;
    const int jlg = (4 * (g + 1) * (g + 2) - 1) / 33;
    const int nsl = jlg - j0g + 1;

    // Phase A: 32 chunks; wave w handles 8
    #pragma unroll
    for (int c4 = 0; c4 < 8; ++c4) {
        const int idx = w * 8 + c4;
        const int tokt = idx >> 4, dt = idx & 15;
        const int tloc = tloc_base + tokt;
        f32x4 s = f32x4{0.f, 0.f, 0.f, 0.f};
        for (int sl = 0; sl < nsl; ++sl) {
            const u16* p = part + ((((size_t)b * MAXOFF + off + sl) * 8 + tloc) * 16 + dt) * 256 + lane * 4;
            bf16x4 pv = *(const bf16x4*)p;
            s[0] += b2f(pv[0]); s[1] += b2f(pv[1]);
            s[2] += b2f(pv[2]); s[3] += b2f(pv[3]);
        }
        bf16x4 t;
        t[0] = (short)f2b(s[0]); t[1] = (short)f2b(s[1]);
        t[2] = (short)f2b(s[2]); t[3] = (short)f2b(s[3]);
        *(bf16x4*)&cb[(tokt * 16 + dt) * 256 + lane * 4] = t;
    }
    __syncthreads();

    // Phase B: wave w -> d-tiles [w*4, w*4+4)
    #pragma unroll
    for (int c4 = 0; c4 < 4; ++c4) {
        const int ct = w * 4 + c4;
        f32x4 acc0 = f32x4{0.f, 0.f, 0.f, 0.f};
        f32x4 acc1 = f32x4{0.f, 0.f, 0.f, 0.f};
        #pragma unroll
        for (int dt = 0; dt < 16; ++dt) {
            bf16x4 A = *(const bf16x4*)(wo16 + (size_t)(ct * 16 + dt) * 256 + lane * 4);
            bf16x4 B0 = *(const bf16x4*)&cb[(0 * 16 + dt) * 256 + lane * 4];
            bf16x4 B1 = *(const bf16x4*)&cb[(1 * 16 + dt) * 256 + lane * 4];
            acc0 = mfma16(A, B0, acc0);
            acc1 = mfma16(A, B1, acc1);
        }
        float* o0 = out + (size_t)(g32 * 32 + 0 * 16 + ln) * DD + ct * 16 + q4 * 4;
        float* o1 = out + (size_t)(g32 * 32 + 1 * 16 + ln) * DD + ct * 16 + q4 * 4;
        *(f32x4*)o0 = acc0;
        *(f32x4*)o1 = acc1;
    }
}

extern "C" void kernel_launch(void* const* d_in, const int* in_sizes, int n_in,
                              void* d_out, int out_size, void* d_ws, size_t ws_size,
                              hipStream_t stream)
{
    const float* x  = (const float*)d_in[0];
    const float* Wq = (const float*)d_in[1];
    const float* Wk = (const float*)d_in[2];
    const float* Wv = (const float*)d_in[3];
    const float* Wo = (const float*)d_in[4];
    float* out = (float*)d_out;

    const size_t nW = (size_t)DD * DD;        // 65536
    const size_t nX = (size_t)BB * LL * DD;   // 4,194,304

    u16* wf   = (u16*)d_ws;                   // Wq,Wk,Wv B-frag order (384 KB)
    u16* wo16 = wf + 3 * nW;                  // Wo K=16 A-frag order (128 KB)
    u16* qfr  = wf + 4 * nW;                  // 8 MB
    u16* kfr  = qfr + nX;                     // 8 MB
    u16* vfr  = kfr + nX;                     // 8 MB
    u16* part = vfr + nX;                     // 4*160*8*16*256 bf16 = 41.9 MB

    wconv_kernel<<<dim3(128), dim3(256), 0, stream>>>(Wq, Wk, Wv, Wo, wf, wo16);
    qkv_kernel<<<dim3(512), dim3(256), 0, stream>>>(x, wf, qfr, kfr, vfr);
    attn_kernel<<<dim3(512), dim3(256), 0, stream>>>(qfr, kfr, vfr, part);
    oproj_kernel<<<dim3(512), dim3(256), 0, stream>>>(part, wo16, out);
}

// Round 12
// 157.111 us; speedup vs baseline: 1.2490x; 1.2030x over previous
//
#include <hip/hip_runtime.h>

#define BB 4
#define LL 4096
#define DD 256
#define MAXOFF 160   // max per-batch partial slots (exact bound: 159)

typedef short bf16x8 __attribute__((ext_vector_type(8)));
typedef short bf16x4 __attribute__((ext_vector_type(4)));
typedef float f32x4 __attribute__((ext_vector_type(4)));
typedef unsigned u32x4 __attribute__((ext_vector_type(4)));
typedef unsigned short u16;

__device__ inline u16 f2b(float f) {
    union { float f; unsigned u; } v; v.f = f;
    unsigned r = (v.u + 0x7fffu + ((v.u >> 16) & 1u)) >> 16;  // RNE
    return (u16)r;
}
__device__ inline float b2f(short s) {
    union { unsigned u; float f; } v; v.u = ((unsigned)(unsigned short)s) << 16;
    return v.f;
}
// pack 2 fp32 -> 2 bf16 (TRUNCATE) in one v_perm_b32
__device__ inline unsigned pk2(float lo, float hi) {
    union { float f; unsigned u; } a, b; a.f = lo; b.f = hi;
    return __builtin_amdgcn_perm(b.u, a.u, 0x07060302u);
}

__device__ inline f32x4 mfma32(bf16x8 a, bf16x8 b, f32x4 c) {
    return __builtin_amdgcn_mfma_f32_16x16x32_bf16(a, b, c, 0, 0, 0);
}
__device__ inline f32x4 mfma16(bf16x4 a, bf16x4 b, f32x4 c) {
    return __builtin_amdgcn_mfma_f32_16x16x16bf16_1k(a, b, c, 0, 0, 0);
}

__device__ inline void gl_lds(const u16* g, u16* l) {
    __builtin_amdgcn_global_load_lds(
        (const __attribute__((address_space(1))) void*)g,
        (__attribute__((address_space(3))) void*)l, 16, 0, 0);
}

// ===========================================================================
// Layouts unchanged from round 11 (frag-order chunk buffers, bf16 partials
// with prefix-offset slots). Round 12: qkv/oproj re-gridded for 4 blocks/CU
// (qkv: 1024 blocks = 512 32-token groups x 2 dim-halves, ONE barrier;
//  oproj: 1024 blocks = one 16-token tile each).
// ===========================================================================

__global__ __launch_bounds__(256) void wconv_kernel(
    const float* __restrict__ Wq, const float* __restrict__ Wk,
    const float* __restrict__ Wv, const float* __restrict__ Wo,
    u16* __restrict__ wf, u16* __restrict__ wo16)
{
    const int w = threadIdx.x >> 6, lane = threadIdx.x & 63;
    const int q4 = lane >> 4, ln = lane & 15;
    const int id = blockIdx.x * 4 + w;          // 0..511
    const int mat = id >> 7, rem = id & 127, ct = rem >> 3, ks = rem & 7;
    if (mat < 3) {
        const float* W = (mat == 0) ? Wq : (mat == 1) ? Wk : Wv;
        const float* src = W + (size_t)(ct * 16 + ln) * DD + ks * 32 + q4 * 8;
        float4 f0 = ((const float4*)src)[0], f1 = ((const float4*)src)[1];
        bf16x8 t;
        t[0] = (short)f2b(f0.x); t[1] = (short)f2b(f0.y);
        t[2] = (short)f2b(f0.z); t[3] = (short)f2b(f0.w);
        t[4] = (short)f2b(f1.x); t[5] = (short)f2b(f1.y);
        t[6] = (short)f2b(f1.z); t[7] = (short)f2b(f1.w);
        *(bf16x8*)(wf + (size_t)mat * 65536 + (ct * 8 + ks) * 512 + lane * 8) = t;
    } else {
        const float* src = Wo + (size_t)(ct * 16 + ln) * DD + ks * 32 + q4 * 4;
        float4 f0 = *(const float4*)src;
        float4 f1 = *(const float4*)(src + 16);
        bf16x4 t0, t1;
        t0[0] = (short)f2b(f0.x); t0[1] = (short)f2b(f0.y);
        t0[2] = (short)f2b(f0.z); t0[3] = (short)f2b(f0.w);
        t1[0] = (short)f2b(f1.x); t1[1] = (short)f2b(f1.y);
        t1[2] = (short)f2b(f1.z); t1[3] = (short)f2b(f1.w);
        *(bf16x4*)(wo16 + (size_t)(ct * 16 + 2 * ks) * 256 + lane * 4) = t0;
        *(bf16x4*)(wo16 + (size_t)(ct * 16 + 2 * ks + 1) * 256 + lane * 4) = t1;
    }
}

// ---------------------------------------------------------------------------
// Kernel 1: QKV projection. 1024 blocks: tg (32 tokens) x half (128 dims);
// 4 blocks/CU. Wave w: token-tile tl = w&1 (16 rows), dim-quarter dq = w>>1
// (4 col-tiles). 96 MFMA/wave, 3 independent acc sets. Epilogues write
// disjoint LDS regions -> ONE barrier, then frag-order stores.
// ---------------------------------------------------------------------------
__global__ __launch_bounds__(256, 4) void qkv_kernel(
    const float* __restrict__ x, const u16* __restrict__ wf,
    u16* __restrict__ qf, u16* __restrict__ kf_, u16* __restrict__ vf_)
{
    __shared__ u16 lt_q[32 * 136];   // [token 32][dim_local 128 +pad]
    __shared__ u16 lt_k[32 * 136];
    __shared__ u16 lt_v[128 * 40];   // [dim_local 128][token 32 +pad]

    const int w = threadIdx.x >> 6, lane = threadIdx.x & 63;
    const int q4 = lane >> 4, ln = lane & 15;
    const int tg = blockIdx.x >> 1, half = blockIdx.x & 1;
    const int tl = w & 1, dq = w >> 1;

    // A-frags: 16 token rows (fp32 -> bf16)
    bf16x8 a[8];
    {
        const float* xrow = x + (size_t)(tg * 32 + tl * 16 + ln) * DD;
        #pragma unroll
        for (int ks = 0; ks < 8; ++ks) {
            const float4* p = (const float4*)(xrow + ks * 32 + q4 * 8);
            float4 f0 = p[0], f1 = p[1];
            bf16x8 t;
            t[0] = (short)f2b(f0.x); t[1] = (short)f2b(f0.y);
            t[2] = (short)f2b(f0.z); t[3] = (short)f2b(f0.w);
            t[4] = (short)f2b(f1.x); t[5] = (short)f2b(f1.y);
            t[6] = (short)f2b(f1.z); t[7] = (short)f2b(f1.w);
            a[ks] = t;
        }
    }

    f32x4 acc0[4], acc1[4], acc2[4];
    #pragma unroll
    for (int cl = 0; cl < 4; ++cl) {
        acc0[cl] = f32x4{0.f, 0.f, 0.f, 0.f};
        acc1[cl] = f32x4{0.f, 0.f, 0.f, 0.f};
        acc2[cl] = f32x4{0.f, 0.f, 0.f, 0.f};
    }

    #pragma unroll
    for (int ks = 0; ks < 8; ++ks) {
        #pragma unroll
        for (int cl = 0; cl < 4; ++cl) {
            const int ct = half * 8 + dq * 4 + cl;
            const size_t off = ((size_t)ct * 8 + ks) * 512 + lane * 8;
            bf16x8 b0 = *(const bf16x8*)(wf + off);
            bf16x8 b1 = *(const bf16x8*)(wf + 65536 + off);
            bf16x8 b2 = *(const bf16x8*)(wf + 131072 + off);
            acc0[cl] = mfma32(a[ks], b0, acc0[cl]);
            acc1[cl] = mfma32(a[ks], b1, acc1[cl]);
            acc2[cl] = mfma32(a[ks], b2, acc2[cl]);
        }
    }

    // C-layout -> LDS (disjoint regions; single barrier after)
    #pragma unroll
    for (int cl = 0; cl < 4; ++cl) {
        const int coll = (dq * 4 + cl) * 16 + ln;   // local dim [0,128)
        #pragma unroll
        for (int r = 0; r < 4; ++r) {
            const int tok = tl * 16 + q4 * 4 + r;   // local token [0,32)
            lt_q[tok * 136 + coll] = f2b(acc0[cl][r]);
            lt_k[tok * 136 + coll] = f2b(acc1[cl][r]);
            lt_v[coll * 40 + tok] = f2b(acc2[cl][r]);
        }
    }
    __syncthreads();

    // Q/K: wave w -> h = w&1, ksl in {2*dq, 2*dq+1}
    {
        const int h = w & 1;
        #pragma unroll
        for (int e = 0; e < 2; ++e) {
            const int ksl = 2 * dq + e;             // local K-chunk [0,4)
            const int ks = half * 4 + ksl;          // global K-chunk [0,8)
            bf16x8 aq = *(const bf16x8*)&lt_q[(h * 16 + ln) * 136 + ksl * 32 + q4 * 8];
            bf16x8 ak = *(const bf16x8*)&lt_k[(h * 16 + ln) * 136 + ksl * 32 + q4 * 8];
            const size_t dst = (size_t)((tg * 2 + h) * 8 + ks) * 512 + lane * 8;
            *(bf16x8*)(qf + dst) = aq;
            *(bf16x8*)(kf_ + dst) = ak;
        }
    }
    // V: wave w -> dt_l in {2w, 2w+1}
    #pragma unroll
    for (int e = 0; e < 2; ++e) {
        const int dt_l = 2 * w + e;                 // local d-tile [0,8)
        bf16x4 lo = *(const bf16x4*)&lt_v[(dt_l * 16 + ln) * 40 + q4 * 4];
        bf16x4 hi = *(const bf16x4*)&lt_v[(dt_l * 16 + ln) * 40 + 16 + q4 * 4];
        bf16x8 t;
        t[0] = lo[0]; t[1] = lo[1]; t[2] = lo[2]; t[3] = lo[3];
        t[4] = hi[0]; t[5] = hi[1]; t[6] = hi[2]; t[7] = hi[3];
        *(bf16x8*)(vf_ + (size_t)(tg * 16 + half * 8 + dt_l) * 512 + lane * 8) = t;
    }
}

// ---------------------------------------------------------------------------
// Kernel 2: causal ReLU attention (unchanged from round 11): 32 queries/wave,
// equal-work flattened segments, K=32 PV MFMA, perm-packed P.
// ---------------------------------------------------------------------------
__global__ __launch_bounds__(256, 2) void attn_kernel(
    const u16* __restrict__ qf, const u16* __restrict__ kfr,
    const u16* __restrict__ vfr, u16* __restrict__ part)
{
    __shared__ u16 buf[2][32][512];   // 64 KB

    const int i = blockIdx.x;
    const int b = (i >> 1) & 3;
    const int j = ((i >> 3) << 1) | (i & 1);    // segment 0..127

    const int w = threadIdx.x >> 6, lane = threadIdx.x & 63;
    const int q4 = lane >> 4, ln = lane & 15;

    const int u0 = (33 * j) >> 1;
    const int u1 = (33 * (j + 1)) >> 1;

    int g = (int)((sqrtf((float)(2 * u0 + 1)) - 1.0f) * 0.5f);
    while (2 * (g + 1) * (g + 2) <= u0) ++g;
    while (2 * g * (g + 1) > u0) --g;
    int kt = u0 - 2 * g * (g + 1);
    int u = u0;

    int off = 0;
    for (int g2 = 0; g2 < g; ++g2) {
        const int j0 = (4 * g2 * (g2 + 1) + 1) / 33;
        const int jl = (4 * (g2 + 1) * (g2 + 2) - 1) / 33;
        off += jl - j0 + 1;
    }

    {
        const size_t cb = (size_t)((b * 128 + kt) * 16) * 512;
        #pragma unroll
        for (int c4 = 0; c4 < 8; ++c4) {
            const int c = w * 8 + c4;
            const u16* gsrc = ((c < 16) ? (kfr + cb + c * 512)
                                        : (vfr + cb + (c - 16) * 512)) + lane * 8;
            gl_lds(gsrc, &buf[u0 & 1][c][0]);
        }
    }

    while (u < u1) {
        const int ktend = 4 * g + 4;
        const int rem = u1 - u;
        const int kt_stop = (ktend < kt + rem) ? ktend : (kt + rem);
        const int t0 = g * 8 + 2 * w;
        const int qg0 = t0 * 16 + ln;
        const int qg1 = qg0 + 16;
        const float inv0 = 1.0f / (float)(qg0 > 1 ? qg0 : 1);
        const float inv1 = 1.0f / (float)qg1;

        bf16x8 qB0[8], qB1[8];
        {
            const u16* qb0 = qf + (size_t)(t0 * 8) * 512 + (size_t)b * (128 * 16 * 512) + lane * 8;
            #pragma unroll
            for (int ks = 0; ks < 8; ++ks) {
                qB0[ks] = *(const bf16x8*)(qb0 + ks * 512);
                qB1[ks] = *(const bf16x8*)(qb0 + (8 + ks) * 512);
            }
        }

        f32x4 oacc0[16], oacc1[16];
        #pragma unroll
        for (int dt = 0; dt < 16; ++dt) {
            oacc0[dt] = f32x4{0.f, 0.f, 0.f, 0.f};
            oacc1[dt] = f32x4{0.f, 0.f, 0.f, 0.f};
        }

        #pragma unroll 1
        for (; kt < kt_stop; ++kt, ++u) {
            const int cur = u & 1;
            __syncthreads();

            if (u + 1 < u1) {
                const int ktn = (kt + 1 < ktend) ? (kt + 1) : 0;
                const size_t cb = (size_t)((b * 128 + ktn) * 16) * 512;
                #pragma unroll
                for (int c4 = 0; c4 < 8; ++c4) {
                    const int c = w * 8 + c4;
                    const u16* gsrc = ((c < 16) ? (kfr + cb + c * 512)
                                                : (vfr + cb + (c - 16) * 512)) + lane * 8;
                    gl_lds(gsrc, &buf[cur ^ 1][c][0]);
                }
            }

            f32x4 s00 = f32x4{0.f, 0.f, 0.f, 0.f};
            f32x4 s10 = f32x4{0.f, 0.f, 0.f, 0.f};
            f32x4 s01 = f32x4{0.f, 0.f, 0.f, 0.f};
            f32x4 s11 = f32x4{0.f, 0.f, 0.f, 0.f};
            #pragma unroll
            for (int ks = 0; ks < 8; ++ks) {
                bf16x8 kf0 = *(const bf16x8*)&buf[cur][ks][lane * 8];
                bf16x8 kf1 = *(const bf16x8*)&buf[cur][8 + ks][lane * 8];
                s00 = mfma32(kf0, qB0[ks], s00);
                s10 = mfma32(kf1, qB0[ks], s10);
                s01 = mfma32(kf0, qB1[ks], s01);
                s11 = mfma32(kf1, qB1[ks], s11);
            }

            const int d0 = kt * 32 + q4 * 4 - qg0;
            float v00[4], v10[4], v01[4], v11[4];
            #pragma unroll
            for (int rr = 0; rr < 4; ++rr) {
                v00[rr] = (d0 + rr > 0)      ? 0.f : fmaxf(s00[rr], 0.f) * inv0;
                v10[rr] = (d0 + 16 + rr > 0) ? 0.f : fmaxf(s10[rr], 0.f) * inv0;
                v01[rr] = (d0 - 16 + rr > 0) ? 0.f : fmaxf(s01[rr], 0.f) * inv1;
                v11[rr] = (d0 + rr > 0)      ? 0.f : fmaxf(s11[rr], 0.f) * inv1;
            }
            union { u32x4 u; bf16x8 h; } c0, c1;
            c0.u[0] = pk2(v00[0], v00[1]); c0.u[1] = pk2(v00[2], v00[3]);
            c0.u[2] = pk2(v10[0], v10[1]); c0.u[3] = pk2(v10[2], v10[3]);
            c1.u[0] = pk2(v01[0], v01[1]); c1.u[1] = pk2(v01[2], v01[3]);
            c1.u[2] = pk2(v11[0], v11[1]); c1.u[3] = pk2(v11[2], v11[3]);

            #pragma unroll
            for (int dt = 0; dt < 16; ++dt) {
                bf16x8 vv = *(const bf16x8*)&buf[cur][16 + dt][lane * 8];
                oacc0[dt] = mfma32(vv, c0.h, oacc0[dt]);
                oacc1[dt] = mfma32(vv, c1.h, oacc1[dt]);
            }
        }

        {
            const int j0g = (4 * g * (g + 1) + 1) / 33;
            const int gslot = off + (j - j0g);
            u16* pb0 = part + ((((size_t)b * MAXOFF + gslot) * 8 + 2 * w) * 16) * 256 + lane * 4;
            u16* pb1 = pb0 + 16 * 256;
            #pragma unroll
            for (int dt = 0; dt < 16; ++dt) {
                bf16x4 t0v, t1v;
                t0v[0] = (short)f2b(oacc0[dt][0]); t0v[1] = (short)f2b(oacc0[dt][1]);
                t0v[2] = (short)f2b(oacc0[dt][2]); t0v[3] = (short)f2b(oacc0[dt][3]);
                t1v[0] = (short)f2b(oacc1[dt][0]); t1v[1] = (short)f2b(oacc1[dt][1]);
                t1v[2] = (short)f2b(oacc1[dt][2]); t1v[3] = (short)f2b(oacc1[dt][3]);
                *(bf16x4*)(pb0 + dt * 256) = t0v;
                *(bf16x4*)(pb1 + dt * 256) = t1v;
            }
            off += ((4 * (g + 1) * (g + 2) - 1) / 33) - j0g + 1;
        }
        ++g;
        kt = 0;
    }
}

// ---------------------------------------------------------------------------
// Kernel 3: fused reduce + output projection. 1024 blocks (16 tokens each),
// 4 blocks/CU. Phase A: sum nsl bf16 partial slots -> LDS (K=16 B-frag).
// Phase B: out^T = Wo ctx^T via mfma16, direct fp32 C-tile stores.
// ---------------------------------------------------------------------------
__global__ __launch_bounds__(256, 4) void oproj_kernel(
    const u16* __restrict__ part, const u16* __restrict__ wo16,
    float* __restrict__ out)
{
    __shared__ u16 cb[16 * 256];   // 8 KB

    const int w = threadIdx.x >> 6, lane = threadIdx.x & 63;
    const int q4 = lane >> 4, ln = lane & 15;
    const int g16 = blockIdx.x;        // 16-token tile, 0..1023
    const int b = g16 >> 8, gb = g16 & 255;
    const int g = gb >> 3;             // 128-query group
    const int tloc = gb & 7;

    int off = 0;
    for (int g2 = 0; g2 < g; ++g2) {
        const int j0 = (4 * g2 * (g2 + 1) + 1) / 33;
        const int jl = (4 * (g2 + 1) * (g2 + 2) - 1) / 33;
        off += jl - j0 + 1;
    }
    const int j0g = (4 * g * (g + 1) + 1) / 33;
    const int jlg = (4 * (g + 1) * (g + 2) - 1) / 33;
    const int nsl = jlg - j0g + 1;

    // Phase A: 16 chunks; wave w handles 4
    #pragma unroll
    for (int c4 = 0; c4 < 4; ++c4) {
        const int dt = w * 4 + c4;
        f32x4 s = f32x4{0.f, 0.f, 0.f, 0.f};
        for (int sl = 0; sl < nsl; ++sl) {
            const u16* p = part + ((((size_t)b * MAXOFF + off + sl) * 8 + tloc) * 16 + dt) * 256 + lane * 4;
            bf16x4 pv = *(const bf16x4*)p;
            s[0] += b2f(pv[0]); s[1] += b2f(pv[1]);
            s[2] += b2f(pv[2]); s[3] += b2f(pv[3]);
        }
        bf16x4 t;
        t[0] = (short)f2b(s[0]); t[1] = (short)f2b(s[1]);
        t[2] = (short)f2b(s[2]); t[3] = (short)f2b(s[3]);
        *(bf16x4*)&cb[dt * 256 + lane * 4] = t;
    }
    __syncthreads();

    // Phase B: wave w -> d-tiles [w*4, w*4+4)
    #pragma unroll
    for (int c4 = 0; c4 < 4; ++c4) {
        const int ct = w * 4 + c4;
        f32x4 acc = f32x4{0.f, 0.f, 0.f, 0.f};
        #pragma unroll
        for (int dt = 0; dt < 16; ++dt) {
            bf16x4 A = *(const bf16x4*)(wo16 + (size_t)(ct * 16 + dt) * 256 + lane * 4);
            bf16x4 B = *(const bf16x4*)&cb[dt * 256 + lane * 4];
            acc = mfma16(A, B, acc);
        }
        float* o = out + (size_t)(g16 * 16 + ln) * DD + ct * 16 + q4 * 4;
        *(f32x4*)o = acc;
    }
}

extern "C" void kernel_launch(void* const* d_in, const int* in_sizes, int n_in,
                              void* d_out, int out_size, void* d_ws, size_t ws_size,
                              hipStream_t stream)
{
    const float* x  = (const float*)d_in[0];
    const float* Wq = (const float*)d_in[1];
    const float* Wk = (const float*)d_in[2];
    const float* Wv = (const float*)d_in[3];
    const float* Wo = (const float*)d_in[4];
    float* out = (float*)d_out;

    const size_t nW = (size_t)DD * DD;        // 65536
    const size_t nX = (size_t)BB * LL * DD;   // 4,194,304

    u16* wf   = (u16*)d_ws;                   // Wq,Wk,Wv B-frag order (384 KB)
    u16* wo16 = wf + 3 * nW;                  // Wo K=16 A-frag order (128 KB)
    u16* qfr  = wf + 4 * nW;                  // 8 MB
    u16* kfr  = qfr + nX;                     // 8 MB
    u16* vfr  = kfr + nX;                     // 8 MB
    u16* part = vfr + nX;                     // 41.9 MB

    wconv_kernel<<<dim3(128), dim3(256), 0, stream>>>(Wq, Wk, Wv, Wo, wf, wo16);
    qkv_kernel<<<dim3(1024), dim3(256), 0, stream>>>(x, wf, qfr, kfr, vfr);
    attn_kernel<<<dim3(512), dim3(256), 0, stream>>>(qfr, kfr, vfr, part);
    oproj_kernel<<<dim3(1024), dim3(256), 0, stream>>>(part, wo16, out);
}